// Round 1
// 146.772 us; speedup vs baseline: 1.0165x; 1.0165x over previous
//
#include <hip/hip_runtime.h>

typedef __attribute__((ext_vector_type(8))) short short8;
typedef __attribute__((ext_vector_type(16))) float f32x16;

// ws layout:
//   Ft2  [z=512][yy=66][xx=66][8] bf16 halo-padded features, z = c*8 + b   (35.68 MB)
//   wt2  [slab=72][e=8][n=128][8] bf16 B slabs, e = i&7 (chunk-major!)     (1.18 MB)
#define FT2_SHORTS (512u * 4356u * 8u)
#define PLANE16    4356

typedef __attribute__((address_space(3))) unsigned int lds_u32_t;
typedef __attribute__((address_space(1))) const unsigned int g_u32_t;

__device__ __forceinline__ unsigned short f2bf(float x) {
    union { float f; unsigned u; } v; v.f = x;
    unsigned r = v.u + 0x7FFFu + ((v.u >> 16) & 1u);   // RNE bf16
    return (unsigned short)(r >> 16);
}

__device__ __forceinline__ void feat8(float p, unsigned short* uf) {
    float e   = __expf(-p);
    float sig = 1.f / (1.f + e);
    uf[0] = f2bf(p * sig);
    float u  = p * 1.5f + 4.5f;
    float fj = floorf(u);
    int   j0 = (int)fj;
    float t  = u - fj;
    bool  inr = (u >= 0.f) && (u < 9.f);
    float t2 = t * t, t3 = t2 * t;
    const float c16 = 1.f / 6.f;
    float r0 = t3 * c16;
    float r1 = (-3.f * t3 + 3.f * t2 + 3.f * t + 1.f) * c16;
    float r2 = (3.f * t3 - 6.f * t2 + 4.f) * c16;
    float s1 = 1.f - t;
    float r3 = s1 * s1 * s1 * c16;
#pragma unroll
    for (int g = 0; g < 6; ++g) {
        int r = j0 - g;
        float v = (r == 0) ? r0 : ((r == 1) ? r1 : ((r == 2) ? r2 : ((r == 3) ? r3 : 0.f)));
        uf[1 + g] = f2bf(inr ? v : 0.f);
    }
    uf[7] = 0;
}

// ---- Fused prep: per block (512): 144 B-chunks + 1 halo plane + 1 feature line ----
__global__ __launch_bounds__(256)
void prep_all(const float* __restrict__ x,
              const float* __restrict__ bw, const float* __restrict__ sw,
              unsigned short* __restrict__ ft, unsigned short* __restrict__ wt) {
    const int blk = blockIdx.x;          // 0..511
    const int tid = threadIdx.x;

    // (1) B prep into chunk-major layout: wt[slab][i&7][n][8]
    if (tid < 144) {
        int idx = blk * 144 + tid;
        int o = idx / 576;
        int i = idx - o * 576;
        int slab = i >> 3, e = i & 7;
        union { unsigned short u[8]; uint4 v; } pk;
        pk.u[0] = f2bf(bw[o * 576 + i]);
        const float* s = sw + (size_t)(o * 576 + i) * 6;
#pragma unroll
        for (int f = 0; f < 6; ++f) pk.u[1 + f] = f2bf(s[f]);
        pk.u[7] = 0;
        *(uint4*)(wt + ((size_t)slab * 8192 + e * 1024 + o * 8)) = pk.v;
    }

    // (2) halo plane z = blk: feat8(0) into the 260 border cells
    {
        short8 pad = { 0, 0, (short)0x3CAB, (short)0x3EF5,
                       (short)0x3EF5, (short)0x3CAB, 0, 0 };
        for (int t = tid; t < 260; t += 256) {
            int yy, xx;
            if (t < 66)       { yy = 0;       xx = t; }
            else if (t < 132) { yy = 65;      xx = t - 66; }
            else if (t < 196) { yy = t - 131; xx = 0; }
            else              { yy = t - 195; xx = 65; }
            ((short8*)ft)[blk * PLANE16 + yy * 66 + xx] = pad;
        }
    }

    // (3) features for line = blk (b = blk>>6, y = blk&63)
    __shared__ float Xl[64 * 65];
    const int b = blk >> 6, y = blk & 63;
    const float* xl = x + (size_t)blk * 4096;
    for (int f4 = tid; f4 < 1024; f4 += 256) {
        float4 v = ((const float4*)xl)[f4];
        int xx = f4 >> 4, c4 = (f4 & 15) << 2;
        float* d = &Xl[xx * 65 + c4];
        d[0] = v.x; d[1] = v.y; d[2] = v.z; d[3] = v.w;
    }
    __syncthreads();
    const int xx = tid & 63;
    const int cw = tid >> 6;
#pragma unroll 4
    for (int p = 0; p < 16; ++p) {
        int c = cw + (p << 2);
        float pv = Xl[xx * 65 + c];
        union { unsigned short u[8]; uint4 v; } pk;
        feat8(pv, pk.u);
        size_t o16 = (size_t)(c * 8 + b) * PLANE16 + (y + 1) * 66 + (xx + 1);
        *(uint4*)(ft + (o16 << 3)) = pk.v;
    }
}

// ---- Main GEMM: tile 256m(4 lines) x 128n, K-split 2, grid 256, block 512 ----
// 8 waves: g = wave>>1 (line 0..3), nh = wave&1 (n-half).
// LDS buffer (48 KB): [B: 8 e-slices x 128n x 16B = 16 KB][A: 32 (i,g) x 64px x 16B = 32 KB]
// TRIPLE-buffered = 144 KB. Depth-3 prefetch with counted vmcnt (T3+T4), raw
// s_barrier (no vmcnt(0) drain in main loop), setprio around MFMA cluster (T5).
#define BUF_SHORTS 24576

#define STAGE(sl, q_)                                                                 \
    {                                                                                 \
        unsigned short* bufq = Bufs + (q_) * BUF_SHORTS;                              \
        const unsigned short* bsrc = wt + (size_t)(slab0 + (sl)) * 8192;              \
        _Pragma("unroll")                                                             \
        for (int r = 0; r < 2; ++r) {                                                 \
            int boff = (r * 8 + wave) * 512 + lane * 8;                               \
            __builtin_amdgcn_global_load_lds((g_u32_t*)(bsrc + boff),                 \
                                             (lds_u32_t*)(bufq + boff), 16, 0, 0);    \
        }                                                                             \
        _Pragma("unroll")                                                             \
        for (int t = 0; t < 4; ++t) {                                                 \
            int idx = wave * 4 + t;          /* 0..31 = i_loc*4 + g2 */               \
            int ia  = (slab0 + (sl)) * 8 + (idx >> 2);                                \
            int g2  = idx & 3;                                                        \
            int c_  = (ia * 7282) >> 16;                                              \
            int i9_ = ia - c_ * 9;                                                    \
            int kh_ = (i9_ * 11) >> 5;                                                \
            int kw_ = i9_ - kh_ * 3;                                                  \
            const unsigned short* asrc = ft +                                         \
                (((size_t)(c_ * 8 + b) * PLANE16 + (y0 + g2 + kh_) * 66 + kw_) << 3)  \
                + lane * 8;                                                           \
            unsigned short* adst = bufq + 8192 + idx * 512 + lane * 8;                \
            __builtin_amdgcn_global_load_lds((g_u32_t*)asrc, (lds_u32_t*)adst,        \
                                             16, 0, 0);                               \
        }                                                                             \
    }

#define KSTEP(s_)                                                                     \
    {                                                                                 \
        int iloc = 2 * (s_) + h;                                                      \
        const unsigned short* Ab = bufr + 8192 + (iloc * 4 + g) * 512;                \
        const unsigned short* Bb = bufr + iloc * 1024;                                \
        short8 a0 = *(const short8*)(Ab + l32 * 8);                                   \
        short8 a1 = *(const short8*)(Ab + (32 + l32) * 8);                            \
        short8 b0 = *(const short8*)(Bb + (nh * 64 + l32) * 8);                       \
        short8 b1 = *(const short8*)(Bb + (nh * 64 + 32 + l32) * 8);                  \
        acc00 = __builtin_amdgcn_mfma_f32_32x32x16_bf16(a0, b0, acc00, 0, 0, 0);      \
        acc01 = __builtin_amdgcn_mfma_f32_32x32x16_bf16(a0, b1, acc01, 0, 0, 0);      \
        acc10 = __builtin_amdgcn_mfma_f32_32x32x16_bf16(a1, b0, acc10, 0, 0, 0);      \
        acc11 = __builtin_amdgcn_mfma_f32_32x32x16_bf16(a1, b1, acc11, 0, 0, 0);      \
    }

// One phase: wait slab it (counted), barrier, compute, barrier, stage it+3.
// n_ must be a literal: 12 in steady state, 6/0 only in the 2-iter tail.
#define PHASE(it_, q_, n_, dostage_)                                                  \
    {                                                                                 \
        asm volatile("s_waitcnt vmcnt(" #n_ ")" ::: "memory");                        \
        __builtin_amdgcn_s_barrier();                                                 \
        asm volatile("" ::: "memory");                                                \
        const unsigned short* bufr = Bufs + (q_) * BUF_SHORTS;                        \
        __builtin_amdgcn_s_setprio(1);                                                \
        KSTEP(0) KSTEP(1) KSTEP(2) KSTEP(3)                                           \
        __builtin_amdgcn_s_setprio(0);                                                \
        asm volatile("" ::: "memory");                                                \
        __builtin_amdgcn_s_barrier();                                                 \
        asm volatile("" ::: "memory");                                                \
        if (dostage_) STAGE((it_) + 3, q_);                                           \
    }

__global__ __launch_bounds__(512, 2)
void convkan_gemm(const unsigned short* __restrict__ ft,
                  const unsigned short* __restrict__ wt,
                  const float* __restrict__ bias,
                  float* __restrict__ out) {
    extern __shared__ unsigned short Bufs[];     // 3 x 24576 shorts = 144 KB

    const int tid  = threadIdx.x;
    const int blk  = blockIdx.x;                 // 256 blocks
    const int kk   = blk & 1;                    // K-half (channel split)
    const int mb   = blk >> 1;                   // 0..127 (4 lines each)
    const int lane = tid & 63;
    const int wave = tid >> 6;                   // 0..7
    const int g    = wave >> 1;                  // line within tile (0..3)
    const int nh   = wave & 1;                   // n-half (64)
    const int l32  = lane & 31;
    const int h    = lane >> 5;                  // k-half

    const int b  = mb >> 4;
    const int y0 = (mb & 15) << 2;
    const int slab0 = kk * 36;

    f32x16 acc00, acc01, acc10, acc11;
#pragma unroll
    for (int e = 0; e < 16; ++e) { acc00[e] = 0.f; acc01[e] = 0.f; acc10[e] = 0.f; acc11[e] = 0.f; }

    // prologue: fill the 3-deep pipeline
    STAGE(0, 0);
    STAGE(1, 1);
    STAGE(2, 2);

    // steady state: 11 x 3 phases (it = 0..32)
    for (int it3 = 0; it3 < 11; ++it3) {
        const int it = it3 * 3;
        PHASE(it + 0, 0, 12, true)
        PHASE(it + 1, 1, 12, true)
        PHASE(it + 2, 2, 12, true)
    }
    // tail: it = 33, 34, 35 — drain pipeline
    PHASE(33, 0, 12, false)
    PHASE(34, 1, 6,  false)
    PHASE(35, 2, 0,  false)

    // epilogue: C/D row = (r&3)+8*(r>>2)+4*h, col = l32; accumulate via f32 atomics
    const float bv0 = kk ? 0.f : bias[nh * 64 + l32];
    const float bv1 = kk ? 0.f : bias[nh * 64 + 32 + l32];
    const int prow = (mb * 4 + g) * 64;          // output pixel-row base for this wave
    const int ncol = nh * 64 + l32;
#pragma unroll
    for (int r = 0; r < 16; ++r) {
        int mrow = (r & 3) + ((r >> 2) << 3) + 4 * h;
        float* p0 = out + (size_t)(prow + mrow) * 128 + ncol;
        float* p1 = out + (size_t)(prow + 32 + mrow) * 128 + ncol;
        atomicAdd(p0,      acc00[r] + bv0);
        atomicAdd(p0 + 32, acc01[r] + bv1);
        atomicAdd(p1,      acc10[r] + bv0);
        atomicAdd(p1 + 32, acc11[r] + bv1);
    }
}

extern "C" void kernel_launch(void* const* d_in, const int* in_sizes, int n_in,
                              void* d_out, int out_size, void* d_ws, size_t ws_size,
                              hipStream_t stream) {
    (void)in_sizes; (void)n_in; (void)ws_size;
    const float* x        = (const float*)d_in[0];
    const float* base_w   = (const float*)d_in[1];
    const float* spline_w = (const float*)d_in[2];
    const float* bias     = (const float*)d_in[3];
    float* out = (float*)d_out;

    unsigned short* ft = (unsigned short*)d_ws;      // 35.68 MB halo features
    unsigned short* wt = ft + FT2_SHORTS;            // 1.18 MB tiled B

    hipMemsetAsync(out, 0, (size_t)out_size * sizeof(float), stream);
    hipLaunchKernelGGL(prep_all, dim3(512), dim3(256), 0, stream,
                       x, base_w, spline_w, ft, wt);

    const int shmem = 3 * BUF_SHORTS * 2;            // 144 KB
    (void)hipFuncSetAttribute((const void*)convkan_gemm,
                              hipFuncAttributeMaxDynamicSharedMemorySize, shmem);
    hipLaunchKernelGGL(convkan_gemm, dim3(256), dim3(512), shmem, stream,
                       ft, wt, bias, out);
}

// Round 2
// 140.652 us; speedup vs baseline: 1.0608x; 1.0435x over previous
//
#include <hip/hip_runtime.h>

typedef __attribute__((ext_vector_type(8))) short short8;
typedef __attribute__((ext_vector_type(16))) float f32x16;

// ws layout:
//   Ft2  [z=512][yy=66][xx=66][8] bf16 halo-padded features, z = c*8 + b   (35.68 MB)
//   wt2  [slab=72][e=8][n=128][8] bf16 B slabs, e = i&7 (chunk-major!)     (1.18 MB)
#define FT2_SHORTS (512u * 4356u * 8u)
#define PLANE16    4356

typedef __attribute__((address_space(3))) unsigned int lds_u32_t;
typedef __attribute__((address_space(1))) const unsigned int g_u32_t;

__device__ __forceinline__ unsigned short f2bf(float x) {
    union { float f; unsigned u; } v; v.f = x;
    unsigned r = v.u + 0x7FFFu + ((v.u >> 16) & 1u);   // RNE bf16
    return (unsigned short)(r >> 16);
}

__device__ __forceinline__ void feat8(float p, unsigned short* uf) {
    float e   = __expf(-p);
    float sig = 1.f / (1.f + e);
    uf[0] = f2bf(p * sig);
    float u  = p * 1.5f + 4.5f;
    float fj = floorf(u);
    int   j0 = (int)fj;
    float t  = u - fj;
    bool  inr = (u >= 0.f) && (u < 9.f);
    float t2 = t * t, t3 = t2 * t;
    const float c16 = 1.f / 6.f;
    float r0 = t3 * c16;
    float r1 = (-3.f * t3 + 3.f * t2 + 3.f * t + 1.f) * c16;
    float r2 = (3.f * t3 - 6.f * t2 + 4.f) * c16;
    float s1 = 1.f - t;
    float r3 = s1 * s1 * s1 * c16;
#pragma unroll
    for (int g = 0; g < 6; ++g) {
        int r = j0 - g;
        float v = (r == 0) ? r0 : ((r == 1) ? r1 : ((r == 2) ? r2 : ((r == 3) ? r3 : 0.f)));
        uf[1 + g] = f2bf(inr ? v : 0.f);
    }
    uf[7] = 0;
}

// ---- Fused prep: per block (512): 144 B-chunks + 1 halo plane + 1 feature line ----
__global__ __launch_bounds__(256)
void prep_all(const float* __restrict__ x,
              const float* __restrict__ bw, const float* __restrict__ sw,
              unsigned short* __restrict__ ft, unsigned short* __restrict__ wt) {
    const int blk = blockIdx.x;          // 0..511
    const int tid = threadIdx.x;

    // (1) B prep into chunk-major layout: wt[slab][i&7][n][8]
    if (tid < 144) {
        int idx = blk * 144 + tid;
        int o = idx / 576;
        int i = idx - o * 576;
        int slab = i >> 3, e = i & 7;
        union { unsigned short u[8]; uint4 v; } pk;
        pk.u[0] = f2bf(bw[o * 576 + i]);
        const float* s = sw + (size_t)(o * 576 + i) * 6;
#pragma unroll
        for (int f = 0; f < 6; ++f) pk.u[1 + f] = f2bf(s[f]);
        pk.u[7] = 0;
        *(uint4*)(wt + ((size_t)slab * 8192 + e * 1024 + o * 8)) = pk.v;
    }

    // (2) halo plane z = blk: feat8(0) into the 260 border cells
    {
        short8 pad = { 0, 0, (short)0x3CAB, (short)0x3EF5,
                       (short)0x3EF5, (short)0x3CAB, 0, 0 };
        for (int t = tid; t < 260; t += 256) {
            int yy, xx;
            if (t < 66)       { yy = 0;       xx = t; }
            else if (t < 132) { yy = 65;      xx = t - 66; }
            else if (t < 196) { yy = t - 131; xx = 0; }
            else              { yy = t - 195; xx = 65; }
            ((short8*)ft)[blk * PLANE16 + yy * 66 + xx] = pad;
        }
    }

    // (3) features for line = blk (b = blk>>6, y = blk&63)
    __shared__ float Xl[64 * 65];
    const int b = blk >> 6, y = blk & 63;
    const float* xl = x + (size_t)blk * 4096;
    for (int f4 = tid; f4 < 1024; f4 += 256) {
        float4 v = ((const float4*)xl)[f4];
        int xx = f4 >> 4, c4 = (f4 & 15) << 2;
        float* d = &Xl[xx * 65 + c4];
        d[0] = v.x; d[1] = v.y; d[2] = v.z; d[3] = v.w;
    }
    __syncthreads();
    const int xx = tid & 63;
    const int cw = tid >> 6;
#pragma unroll 4
    for (int p = 0; p < 16; ++p) {
        int c = cw + (p << 2);
        float pv = Xl[xx * 65 + c];
        union { unsigned short u[8]; uint4 v; } pk;
        feat8(pv, pk.u);
        size_t o16 = (size_t)(c * 8 + b) * PLANE16 + (y + 1) * 66 + (xx + 1);
        *(uint4*)(ft + (o16 << 3)) = pk.v;
    }
}

// ---- Main GEMM: tile 128m(2 lines) x 128n, FULL K (72 slabs), grid 256, block 512 ----
// No K-split -> no atomics, no out memset. 8 waves: g = wave>>1 (32m group 0..3),
// nh = wave&1 (n-half). Per wave: 2 accs (32m x 64n), 8 MFMA/slab.
// LDS buffer (32 KB): [B: 8 e-slices x 128n x 16B = 16 KB][A: 16 (i,line) x 64px x 16B = 16 KB]
// TRIPLE-buffered = 96 KB. Counted vmcnt (4 loads/thread/slab -> steady vmcnt(8)),
// raw s_barrier, setprio around MFMA cluster.
#define BUF_SHORTS 16384

#define STAGE(sl, q_)                                                                 \
    {                                                                                 \
        unsigned short* bufq = Bufs + (q_) * BUF_SHORTS;                              \
        const unsigned short* bsrc = wt + (size_t)(sl) * 8192;                        \
        _Pragma("unroll")                                                             \
        for (int t = 0; t < 4; ++t) {                                                 \
            int u = wave * 4 + t;            /* 0..31: u<16 = B, u>=16 = A */         \
            if (u < 16) {                                                             \
                int boff = u * 512 + lane * 8;                                        \
                __builtin_amdgcn_global_load_lds((g_u32_t*)(bsrc + boff),             \
                                                 (lds_u32_t*)(bufq + boff), 16, 0, 0);\
            } else {                                                                  \
                int ua  = u - 16;            /* i*2 + line */                         \
                int ia  = (sl) * 8 + (ua >> 1);                                       \
                int ln  = ua & 1;                                                     \
                int c_  = (ia * 7282) >> 16;                                          \
                int i9_ = ia - c_ * 9;                                                \
                int kh_ = (i9_ * 11) >> 5;                                            \
                int kw_ = i9_ - kh_ * 3;                                              \
                const unsigned short* asrc = ft +                                     \
                    (((size_t)(c_ * 8 + b) * PLANE16 + (y0 + ln + kh_) * 66 + kw_)    \
                     << 3) + lane * 8;                                                \
                unsigned short* adst = bufq + 8192 + ua * 512 + lane * 8;             \
                __builtin_amdgcn_global_load_lds((g_u32_t*)asrc, (lds_u32_t*)adst,    \
                                                 16, 0, 0);                           \
            }                                                                         \
        }                                                                             \
    }

#define KSTEP(s_)                                                                     \
    {                                                                                 \
        int iloc = 2 * (s_) + h;             /* e-slice 0..7 */                       \
        const unsigned short* Ab = bufr + 8192 + ((iloc << 1) + gl) * 512;            \
        const unsigned short* Bb = bufr + iloc * 1024;                                \
        short8 a0 = *(const short8*)(Ab + (gh * 32 + l32) * 8);                       \
        short8 b0 = *(const short8*)(Bb + (nh * 64 + l32) * 8);                       \
        short8 b1 = *(const short8*)(Bb + (nh * 64 + 32 + l32) * 8);                  \
        acc0 = __builtin_amdgcn_mfma_f32_32x32x16_bf16(a0, b0, acc0, 0, 0, 0);        \
        acc1 = __builtin_amdgcn_mfma_f32_32x32x16_bf16(a0, b1, acc1, 0, 0, 0);        \
    }

// One phase: wait slab it (counted), barrier, compute, barrier, stage it+3.
#define PHASE(it_, q_, n_, dostage_)                                                  \
    {                                                                                 \
        asm volatile("s_waitcnt vmcnt(" #n_ ")" ::: "memory");                        \
        __builtin_amdgcn_s_barrier();                                                 \
        asm volatile("" ::: "memory");                                                \
        const unsigned short* bufr = Bufs + (q_) * BUF_SHORTS;                        \
        __builtin_amdgcn_s_setprio(1);                                                \
        KSTEP(0) KSTEP(1) KSTEP(2) KSTEP(3)                                           \
        __builtin_amdgcn_s_setprio(0);                                                \
        asm volatile("" ::: "memory");                                                \
        __builtin_amdgcn_s_barrier();                                                 \
        asm volatile("" ::: "memory");                                                \
        if (dostage_) STAGE((it_) + 3, q_);                                           \
    }

__global__ __launch_bounds__(512, 2)
void convkan_gemm(const unsigned short* __restrict__ ft,
                  const unsigned short* __restrict__ wt,
                  const float* __restrict__ bias,
                  float* __restrict__ out) {
    extern __shared__ unsigned short Bufs[];     // 3 x 16384 shorts = 96 KB

    const int tid  = threadIdx.x;
    const int mb   = blockIdx.x;                 // 0..255, 128 px (2 lines) each
    const int lane = tid & 63;
    const int wave = tid >> 6;                   // 0..7
    const int g    = wave >> 1;                  // 32m group (0..3)
    const int nh   = wave & 1;                   // n-half (64)
    const int gl   = g >> 1;                     // line within tile (0..1)
    const int gh   = g & 1;                      // px-half within line
    const int l32  = lane & 31;
    const int h    = lane >> 5;                  // k-half

    const int b  = mb >> 5;                      // image 0..7
    const int y0 = (mb & 31) << 1;               // first of 2 lines

    f32x16 acc0, acc1;
#pragma unroll
    for (int e = 0; e < 16; ++e) { acc0[e] = 0.f; acc1[e] = 0.f; }

    // prologue: fill the 3-deep pipeline
    STAGE(0, 0);
    STAGE(1, 1);
    STAGE(2, 2);

    // steady state: 23 x 3 phases (it = 0..68), each stages it+3 (up to slab 71)
    for (int it3 = 0; it3 < 23; ++it3) {
        const int it = it3 * 3;
        PHASE(it + 0, 0, 8, true)
        PHASE(it + 1, 1, 8, true)
        PHASE(it + 2, 2, 8, true)
    }
    // tail: it = 69, 70, 71 — drain pipeline
    PHASE(69, 0, 8, false)
    PHASE(70, 1, 4, false)
    PHASE(71, 2, 0, false)

    // epilogue: plain coalesced stores. C/D row = (r&3)+8*(r>>2)+4*h, col = l32.
    const int ncol = nh * 64 + l32;
    const float bv0 = bias[ncol];
    const float bv1 = bias[ncol + 32];
    const int prow = mb * 128 + g * 32;          // output pixel-row base for this wave
#pragma unroll
    for (int r = 0; r < 16; ++r) {
        int mrow = (r & 3) + ((r >> 2) << 3) + 4 * h;
        float* p = out + (size_t)(prow + mrow) * 128 + ncol;
        p[0]  = acc0[r] + bv0;
        p[32] = acc1[r] + bv1;
    }
}

extern "C" void kernel_launch(void* const* d_in, const int* in_sizes, int n_in,
                              void* d_out, int out_size, void* d_ws, size_t ws_size,
                              hipStream_t stream) {
    (void)in_sizes; (void)n_in; (void)ws_size; (void)out_size;
    const float* x        = (const float*)d_in[0];
    const float* base_w   = (const float*)d_in[1];
    const float* spline_w = (const float*)d_in[2];
    const float* bias     = (const float*)d_in[3];
    float* out = (float*)d_out;

    unsigned short* ft = (unsigned short*)d_ws;      // 35.68 MB halo features
    unsigned short* wt = ft + FT2_SHORTS;            // 1.18 MB tiled B

    hipLaunchKernelGGL(prep_all, dim3(512), dim3(256), 0, stream,
                       x, base_w, spline_w, ft, wt);

    const int shmem = 3 * BUF_SHORTS * 2;            // 96 KB
    (void)hipFuncSetAttribute((const void*)convkan_gemm,
                              hipFuncAttributeMaxDynamicSharedMemorySize, shmem);
    hipLaunchKernelGGL(convkan_gemm, dim3(256), dim3(512), shmem, stream,
                       ft, wt, bias, out);
}

// Round 3
// 133.354 us; speedup vs baseline: 1.1188x; 1.0547x over previous
//
#include <hip/hip_runtime.h>

typedef __attribute__((ext_vector_type(8))) short short8;
typedef __attribute__((ext_vector_type(16))) float f32x16;

// ws layout:
//   Ft2  [z=512][yy=66][xx=66][8] bf16 halo-padded features, z = c*8 + b   (35.68 MB)
//   wt2  [slab=72][e=8][n=128][8] bf16 B slabs, e = i&7 (chunk-major!)     (1.18 MB)
#define FT2_SHORTS (512u * 4356u * 8u)
#define PLANE16    4356

typedef __attribute__((address_space(3))) unsigned int lds_u32_t;
typedef __attribute__((address_space(1))) const unsigned int g_u32_t;

__device__ __forceinline__ unsigned short f2bf(float x) {
    union { float f; unsigned u; } v; v.f = x;
    unsigned r = v.u + 0x7FFFu + ((v.u >> 16) & 1u);   // RNE bf16
    return (unsigned short)(r >> 16);
}

__device__ __forceinline__ void feat8(float p, unsigned short* uf) {
    float e   = __expf(-p);
    float sig = 1.f / (1.f + e);
    uf[0] = f2bf(p * sig);
    float u  = p * 1.5f + 4.5f;
    float fj = floorf(u);
    int   j0 = (int)fj;
    float t  = u - fj;
    bool  inr = (u >= 0.f) && (u < 9.f);
    float t2 = t * t, t3 = t2 * t;
    const float c16 = 1.f / 6.f;
    float r0 = t3 * c16;
    float r1 = (-3.f * t3 + 3.f * t2 + 3.f * t + 1.f) * c16;
    float r2 = (3.f * t3 - 6.f * t2 + 4.f) * c16;
    float s1 = 1.f - t;
    float r3 = s1 * s1 * s1 * c16;
#pragma unroll
    for (int g = 0; g < 6; ++g) {
        int r = j0 - g;
        float v = (r == 0) ? r0 : ((r == 1) ? r1 : ((r == 2) ? r2 : ((r == 3) ? r3 : 0.f)));
        uf[1 + g] = f2bf(inr ? v : 0.f);
    }
    uf[7] = 0;
}

// ---- Fused prep: per block (512): 144 B-chunks + 1 halo plane + 1 feature line ----
__global__ __launch_bounds__(256)
void prep_all(const float* __restrict__ x,
              const float* __restrict__ bw, const float* __restrict__ sw,
              unsigned short* __restrict__ ft, unsigned short* __restrict__ wt) {
    const int blk = blockIdx.x;          // 0..511
    const int tid = threadIdx.x;

    // (1) B prep into chunk-major layout: wt[slab][i&7][n][8]
    if (tid < 144) {
        int idx = blk * 144 + tid;
        int o = idx / 576;
        int i = idx - o * 576;
        int slab = i >> 3, e = i & 7;
        union { unsigned short u[8]; uint4 v; } pk;
        pk.u[0] = f2bf(bw[o * 576 + i]);
        const float* s = sw + (size_t)(o * 576 + i) * 6;
#pragma unroll
        for (int f = 0; f < 6; ++f) pk.u[1 + f] = f2bf(s[f]);
        pk.u[7] = 0;
        *(uint4*)(wt + ((size_t)slab * 8192 + e * 1024 + o * 8)) = pk.v;
    }

    // (2) halo plane z = blk: feat8(0) into the 260 border cells
    {
        short8 pad = { 0, 0, (short)0x3CAB, (short)0x3EF5,
                       (short)0x3EF5, (short)0x3CAB, 0, 0 };
        for (int t = tid; t < 260; t += 256) {
            int yy, xx;
            if (t < 66)       { yy = 0;       xx = t; }
            else if (t < 132) { yy = 65;      xx = t - 66; }
            else if (t < 196) { yy = t - 131; xx = 0; }
            else              { yy = t - 195; xx = 65; }
            ((short8*)ft)[blk * PLANE16 + yy * 66 + xx] = pad;
        }
    }

    // (3) features for line = blk (b = blk>>6, y = blk&63)
    __shared__ float Xl[64 * 65];
    const int b = blk >> 6, y = blk & 63;
    const float* xl = x + (size_t)blk * 4096;
    for (int f4 = tid; f4 < 1024; f4 += 256) {
        float4 v = ((const float4*)xl)[f4];
        int xx = f4 >> 4, c4 = (f4 & 15) << 2;
        float* d = &Xl[xx * 65 + c4];
        d[0] = v.x; d[1] = v.y; d[2] = v.z; d[3] = v.w;
    }
    __syncthreads();
    const int xx = tid & 63;
    const int cw = tid >> 6;
#pragma unroll 4
    for (int p = 0; p < 16; ++p) {
        int c = cw + (p << 2);
        float pv = Xl[xx * 65 + c];
        union { unsigned short u[8]; uint4 v; } pk;
        feat8(pv, pk.u);
        size_t o16 = (size_t)(c * 8 + b) * PLANE16 + (y + 1) * 66 + (xx + 1);
        *(uint4*)(ft + (o16 << 3)) = pk.v;
    }
}

// ---- Main GEMM: tile 128m x 128n, FULL K, grid 256, block 1024 (16 waves) ----
// Wave (kq,mh,nh): kq = wave>>2 owns slab e-chunks {2kq,2kq+1} (4-way K-split),
// (mh,nh) picks the 64x64 output quadrant. Per wave per slab: 4 ds_read_b128 +
// 4 MFMA (1.0 KB LDS per MFMA). 4 waves/SIMD for latency hiding.
// LDS buffer 32 KB: [B: 8 e-chunks x 128n x 16B][A: 8 chunks x 2 lines x 64px x 16B]
// TRIPLE-buffered = 96 KB; counted vmcnt (2 loads/thread/slab -> steady vmcnt(4)).
// Epilogue: 3-round LDS reduction of K-partials, then plain coalesced stores.
#define BUF_SHORTS 16384

#define STAGE(sl, q_)                                                                 \
    {                                                                                 \
        unsigned short* bufq = Bufs + (q_) * BUF_SHORTS;                              \
        const unsigned short* bsrc = wt + (size_t)(sl) * 8192;                        \
        _Pragma("unroll")                                                             \
        for (int t = 0; t < 2; ++t) {                                                 \
            int u = wave * 2 + t;            /* 0..31: u<16 = B, u>=16 = A */         \
            if (u < 16) {                                                             \
                int boff = u * 512 + lane * 8;                                        \
                __builtin_amdgcn_global_load_lds((g_u32_t*)(bsrc + boff),             \
                                                 (lds_u32_t*)(bufq + boff), 16, 0, 0);\
            } else {                                                                  \
                int ua  = u - 16;            /* chunk*2 + line */                     \
                int ia  = (sl) * 8 + (ua >> 1);                                       \
                int ln  = ua & 1;                                                     \
                int c_  = (ia * 7282) >> 16;                                          \
                int i9_ = ia - c_ * 9;                                                \
                int kh_ = (i9_ * 11) >> 5;                                            \
                int kw_ = i9_ - kh_ * 3;                                              \
                const unsigned short* asrc = ft +                                     \
                    (((size_t)(c_ * 8 + b) * PLANE16 + (y0 + ln + kh_) * 66 + kw_)    \
                     << 3) + lane * 8;                                                \
                unsigned short* adst = bufq + 8192 + ua * 512 + lane * 8;             \
                __builtin_amdgcn_global_load_lds((g_u32_t*)asrc, (lds_u32_t*)adst,    \
                                                 16, 0, 0);                           \
            }                                                                         \
        }                                                                             \
    }

#define COMPUTE(q_)                                                                   \
    {                                                                                 \
        const unsigned short* bufr = Bufs + (q_) * BUF_SHORTS;                        \
        const unsigned short* Ab = bufr + 8192 + ((iloc << 1) + mh) * 512;            \
        const unsigned short* Bb = bufr + iloc * 1024 + nh * 512;                     \
        short8 a0 = *(const short8*)(Ab + l32 * 8);                                   \
        short8 a1 = *(const short8*)(Ab + 256 + l32 * 8);                             \
        short8 b0 = *(const short8*)(Bb + l32 * 8);                                   \
        short8 b1 = *(const short8*)(Bb + 256 + l32 * 8);                             \
        acc00 = __builtin_amdgcn_mfma_f32_32x32x16_bf16(a0, b0, acc00, 0, 0, 0);      \
        acc01 = __builtin_amdgcn_mfma_f32_32x32x16_bf16(a0, b1, acc01, 0, 0, 0);      \
        acc10 = __builtin_amdgcn_mfma_f32_32x32x16_bf16(a1, b0, acc10, 0, 0, 0);      \
        acc11 = __builtin_amdgcn_mfma_f32_32x32x16_bf16(a1, b1, acc11, 0, 0, 0);      \
    }

#define PHASE(q_, n_, stagesl, dostage_)                                              \
    {                                                                                 \
        asm volatile("s_waitcnt vmcnt(" #n_ ")" ::: "memory");                        \
        __builtin_amdgcn_s_barrier();                                                 \
        asm volatile("" ::: "memory");                                                \
        __builtin_amdgcn_s_setprio(1);                                                \
        COMPUTE(q_)                                                                   \
        __builtin_amdgcn_s_setprio(0);                                                \
        asm volatile("" ::: "memory");                                                \
        __builtin_amdgcn_s_barrier();                                                 \
        asm volatile("" ::: "memory");                                                \
        if (dostage_) STAGE(stagesl, q_);                                             \
    }

// Epilogue reduce helpers: conflict-free float4 layout (lane-stride 16 B).
#define DUMPA(base_, A_)                                                              \
    {   float4* s4 = (float4*)(red + (base_));                                        \
        _Pragma("unroll")                                                             \
        for (int c = 0; c < 4; ++c)                                                   \
            s4[c * 64 + lane] = make_float4(A_[4*c], A_[4*c+1], A_[4*c+2], A_[4*c+3]); }
#define ADDA(base_, A_)                                                               \
    {   const float4* s4 = (const float4*)(red + (base_));                            \
        _Pragma("unroll")                                                             \
        for (int c = 0; c < 4; ++c) {                                                 \
            float4 rv = s4[c * 64 + lane];                                            \
            A_[4*c] += rv.x; A_[4*c+1] += rv.y; A_[4*c+2] += rv.z; A_[4*c+3] += rv.w; } }

__global__ __launch_bounds__(1024, 4)
void convkan_gemm(const unsigned short* __restrict__ ft,
                  const unsigned short* __restrict__ wt,
                  const float* __restrict__ bias,
                  float* __restrict__ out) {
    extern __shared__ unsigned short Bufs[];     // 3 x 16384 shorts = 96 KB

    const int tid  = threadIdx.x;
    const int mb   = blockIdx.x;                 // 0..255, 128 px (2 lines) each
    const int lane = tid & 63;
    const int wave = tid >> 6;                   // 0..15
    const int kq   = wave >> 2;                  // K-quarter (e-chunk pair) 0..3
    const int mh   = (wave >> 1) & 1;            // m-half (64 px)
    const int nh   = wave & 1;                   // n-half (64 ch)
    const int l32  = lane & 31;
    const int h    = lane >> 5;                  // k-sub-half within MFMA
    const int iloc = (kq << 1) + h;              // e-chunk this half-wave consumes

    const int b  = mb >> 5;                      // image 0..7
    const int y0 = (mb & 31) << 1;               // first of 2 lines

    f32x16 acc00, acc01, acc10, acc11;
#pragma unroll
    for (int e = 0; e < 16; ++e) { acc00[e] = 0.f; acc01[e] = 0.f; acc10[e] = 0.f; acc11[e] = 0.f; }

    // prologue: fill the 3-deep pipeline
    STAGE(0, 0);
    STAGE(1, 1);
    STAGE(2, 2);

    // steady state: 23 x 3 phases (it = 0..68), staging it+3 (last = slab 71)
    for (int it3 = 0; it3 < 23; ++it3) {
        const int it = it3 * 3;
        PHASE(0, 4, it + 3, true)
        PHASE(1, 4, it + 4, true)
        PHASE(2, 4, it + 5, true)
    }
    // tail: it = 69, 70, 71 — drain pipeline
    PHASE(0, 4, 0, false)
    PHASE(1, 2, 0, false)
    PHASE(2, 0, 0, false)

    // ---- K-partial reduction across kq (3 rounds via LDS), then store ----
    __syncthreads();
    float* red = (float*)Bufs;
    const int grp = mh * 2 + nh;                 // 0..3

    if (kq >= 2) { DUMPA(((grp << 1) + (kq - 2)) * 2048,        acc00);
                   DUMPA(((grp << 1) + (kq - 2)) * 2048 + 1024, acc01); }
    __syncthreads();
    if (kq < 2)  { ADDA(((grp << 1) + kq) * 2048,        acc00);
                   ADDA(((grp << 1) + kq) * 2048 + 1024, acc01); }
    __syncthreads();
    if (kq >= 2) { DUMPA(((grp << 1) + (kq - 2)) * 2048,        acc10);
                   DUMPA(((grp << 1) + (kq - 2)) * 2048 + 1024, acc11); }
    __syncthreads();
    if (kq < 2)  { ADDA(((grp << 1) + kq) * 2048,        acc10);
                   ADDA(((grp << 1) + kq) * 2048 + 1024, acc11); }
    __syncthreads();
    if (kq == 1) { DUMPA(grp * 4096,        acc00); DUMPA(grp * 4096 + 1024, acc01);
                   DUMPA(grp * 4096 + 2048, acc10); DUMPA(grp * 4096 + 3072, acc11); }
    __syncthreads();
    if (kq == 0) {
        ADDA(grp * 4096,        acc00); ADDA(grp * 4096 + 1024, acc01);
        ADDA(grp * 4096 + 2048, acc10); ADDA(grp * 4096 + 3072, acc11);

        const int ncol = nh * 64 + l32;
        const float bv0 = bias[ncol];
        const float bv1 = bias[ncol + 32];
        const int prow = mb * 128 + mh * 64;
#pragma unroll
        for (int r = 0; r < 16; ++r) {
            int mrow = (r & 3) + ((r >> 2) << 3) + 4 * h;
            float* p = out + (size_t)(prow + mrow) * 128 + ncol;
            p[0]  = acc00[r] + bv0;
            p[32] = acc01[r] + bv1;
            float* p2 = out + (size_t)(prow + 32 + mrow) * 128 + ncol;
            p2[0]  = acc10[r] + bv0;
            p2[32] = acc11[r] + bv1;
        }
    }
}

extern "C" void kernel_launch(void* const* d_in, const int* in_sizes, int n_in,
                              void* d_out, int out_size, void* d_ws, size_t ws_size,
                              hipStream_t stream) {
    (void)in_sizes; (void)n_in; (void)ws_size; (void)out_size;
    const float* x        = (const float*)d_in[0];
    const float* base_w   = (const float*)d_in[1];
    const float* spline_w = (const float*)d_in[2];
    const float* bias     = (const float*)d_in[3];
    float* out = (float*)d_out;

    unsigned short* ft = (unsigned short*)d_ws;      // 35.68 MB halo features
    unsigned short* wt = ft + FT2_SHORTS;            // 1.18 MB tiled B

    hipLaunchKernelGGL(prep_all, dim3(512), dim3(256), 0, stream,
                       x, base_w, spline_w, ft, wt);

    const int shmem = 3 * BUF_SHORTS * 2;            // 96 KB
    (void)hipFuncSetAttribute((const void*)convkan_gemm,
                              hipFuncAttributeMaxDynamicSharedMemorySize, shmem);
    hipLaunchKernelGGL(convkan_gemm, dim3(256), dim3(1024), shmem, stream,
                       ft, wt, bias, out);
}